// Round 5
// baseline (752.323 us; speedup 1.0000x reference)
//
#include <hip/hip_runtime.h>
#include <cstdint>
#include <cstddef>

// B=64, S=2048, H=512.  M = B*S = 131072 rows.
#define S_DIM 2048

typedef __attribute__((ext_vector_type(8))) short short8;   // 8 bf16 = 4 VGPR
typedef __attribute__((ext_vector_type(4))) float f32x4;    // MFMA 16x16 accum

static __device__ __forceinline__ unsigned short f2bf(float f) {
  union { float f; unsigned int u; } v; v.f = f;
  unsigned int r = (v.u + 0x7fffu + ((v.u >> 16) & 1u)) >> 16;  // RNE
  return (unsigned short)r;
}

static __device__ __forceinline__ float bf2f(unsigned short u) {
  union { unsigned int u; float f; } v; v.u = ((unsigned int)u) << 16;
  return v.f;
}

// pack 2 f32 -> 2 bf16 in one u32 (RNE), single VALU inst
static __device__ __forceinline__ unsigned int cvt_pk_bf16(float lo, float hi) {
  unsigned int r;
  asm("v_cvt_pk_bf16_f32 %0, %1, %2" : "=v"(r) : "v"(lo), "v"(hi));
  return r;
}

static __device__ __forceinline__ float fast_tanh(float x) {
  x = fminf(15.f, fmaxf(-15.f, x));
  float e = __expf(x + x);
  return 1.f - 2.f * __builtin_amdgcn_rcpf(e + 1.f);
}

static __device__ __forceinline__ void gload_lds16(const void* g, void* l) {
  __builtin_amdgcn_global_load_lds(
      (const __attribute__((address_space(1))) void*)g,
      (__attribute__((address_space(3))) void*)l, 16, 0, 0);
}

// =====================  PACKED B LAYOUT  =====================
// wkp[k0*16384 + g*512 + lane*8 + e] = W[g*16 + (lane&15)][k0*32 + (lane>>4)*8 + e]
// (keys-half of W, row stride 1024). Frag (k0, col-group g) = contiguous 1KB.
__global__ __launch_bounds__(256) void pack_b_kernel(
    const float* __restrict__ W1, const float* __restrict__ W2,
    unsigned short* __restrict__ wkp1, unsigned short* __restrict__ wkp2) {
  int j = blockIdx.x * 256 + threadIdx.x;            // 0 .. 65535
  const float* W = (j < 32768) ? W1 : W2;
  unsigned short* o = (j < 32768) ? wkp1 : wkp2;
  int wt = j & 32767;
  int k0 = wt >> 11, g = (wt >> 6) & 31, lhi = (wt >> 4) & 3, l15 = wt & 15;
  const float* src = W + (size_t)(g * 16 + l15) * 1024 + k0 * 32 + lhi * 8;
  float4 f0 = *reinterpret_cast<const float4*>(src);
  float4 f1 = *reinterpret_cast<const float4*>(src + 4);
  short8 hv;
  hv[0] = (short)f2bf(f0.x); hv[1] = (short)f2bf(f0.y);
  hv[2] = (short)f2bf(f0.z); hv[3] = (short)f2bf(f0.w);
  hv[4] = (short)f2bf(f1.x); hv[5] = (short)f2bf(f1.y);
  hv[6] = (short)f2bf(f1.z); hv[7] = (short)f2bf(f1.w);
  *reinterpret_cast<short8*>(o + (size_t)wt * 8) = hv;
}

// =====================  MEGA: scores1 + P2 in one pass  =====================
// Persistent: 256 blocks, each loops 8 tiles of 64 rows. Per tile, N=1024
// (waves 0-3: W1 cols, waves 4-7: W2 cols), K=512 in 2 halves.
// A staged as f32 via global_load_lds (source-swizzled: cseg = lane ^ wid),
// double-buffered; DMA chunks issued 1/thread/k0-step BEFORE B prefetch so
// in-order vmcnt retirement never stalls on undone staging.
#define MEGA_K0(CUR, NXT, K0L)                                                 \
  {                                                                            \
    if (do_stage) {                                                            \
      const float* ssrc =                                                      \
          keys + (size_t)(strow + (K0L) * 8 + wid) * 512 + skb + cs * 4;       \
      gload_lds16(ssrc,                                                        \
                  lds_c + (size_t)nbuf * 65536 + ((K0L) * 512 + tid) * 16);    \
    }                                                                          \
    if ((K0L) < 7) {                                                           \
      _Pragma("unroll")                                                        \
      for (int nc = 0; nc < 8; ++nc)                                           \
        NXT[nc] = *reinterpret_cast<const short8*>(                            \
            wb_half + ((K0L) + 1) * 16384 + nc * 512);                         \
    }                                                                          \
    _Pragma("unroll")                                                          \
    for (int mr = 0; mr < 4; ++mr) {                                           \
      const int r = mr * 16 + l15;                                             \
      const int tc = (K0L) * 8 + lhi * 2;                                      \
      const int x = r & 7;                                                     \
      const char* hb = lds_c + (size_t)half * 65536;                           \
      f32x4 f0 = *reinterpret_cast<const f32x4*>(                              \
          hb + r * 1024 + ((tc ^ x) << 4));                                    \
      f32x4 f1 = *reinterpret_cast<const f32x4*>(                              \
          hb + r * 1024 + ((((K0L) * 8 + lhi * 2 + 1)) ^ x) * 16);             \
      union { unsigned int u[4]; short8 s; } av;                               \
      av.u[0] = cvt_pk_bf16(f0[0], f0[1]);                                     \
      av.u[1] = cvt_pk_bf16(f0[2], f0[3]);                                     \
      av.u[2] = cvt_pk_bf16(f1[0], f1[1]);                                     \
      av.u[3] = cvt_pk_bf16(f1[2], f1[3]);                                     \
      _Pragma("unroll")                                                        \
      for (int nc = 0; nc < 8; ++nc)                                           \
        acc[mr][nc] = __builtin_amdgcn_mfma_f32_16x16x32_bf16(                 \
            av.s, CUR[nc], acc[mr][nc], 0, 0, 0);                              \
    }                                                                          \
  }

__global__ __launch_bounds__(512, 2) void mega_kernel(
    const float* __restrict__ keys,
    const unsigned short* __restrict__ wkp1,
    const unsigned short* __restrict__ wkp2,
    const float* __restrict__ v1, const float* __restrict__ qp1,
    float* __restrict__ scores1, unsigned short* __restrict__ p2p) {
  __shared__ __align__(16) float lds_f[2][64 * 256];   // 2 x 64 KB f32 A halves
  __shared__ float lds_score[4][64];
  char* lds_c = (char*)&lds_f[0][0];

  const int tid  = threadIdx.x;
  const int wid  = tid >> 6;
  const int lane = tid & 63;
  const int l15  = lane & 15;
  const int lhi  = lane >> 4;
  const int bid  = blockIdx.x;          // 0..255
  const int strip = wid & 3;
  const bool isW2 = wid >= 4;
  const unsigned short* wkp = isW2 ? wkp2 : wkp1;
  const unsigned short* wbase = wkp + (size_t)strip * 4096 + (size_t)lane * 8;
  const int cs = lane ^ wid;            // swizzled source chunk (involution)

  // prologue: stage tile0 half0 into buf0
  {
    const int trow = bid * 512;
    #pragma unroll
    for (int k0l = 0; k0l < 8; ++k0l) {
      const float* ssrc = keys + (size_t)(trow + k0l * 8 + wid) * 512 + cs * 4;
      gload_lds16(ssrc, lds_c + ((k0l * 512 + tid) * 16));
    }
  }
  __syncthreads();

  #pragma unroll 1
  for (int it = 0; it < 8; ++it) {
    const int tile = bid * 8 + it;
    const int row0 = tile * 64;
    const int b    = row0 >> 11;

    f32x4 acc[4][8];
    #pragma unroll
    for (int mr = 0; mr < 4; ++mr)
      #pragma unroll
      for (int nc = 0; nc < 8; ++nc) {
        f32x4 z = {0.f, 0.f, 0.f, 0.f};
        acc[mr][nc] = z;
      }

    #pragma unroll
    for (int half = 0; half < 2; ++half) {
      const bool do_stage = (half == 0) || (it < 7);
      const int strow = (half == 0) ? row0 : (row0 + 64);   // next stage target rows
      const int skb   = (half == 0) ? 256 : 0;              // next stage K-base (f32)
      const int nbuf  = half ^ 1;
      const unsigned short* wb_half = wbase + (size_t)half * 8 * 16384;

      short8 b0[8], b1[8];
      #pragma unroll
      for (int nc = 0; nc < 8; ++nc)
        b0[nc] = *reinterpret_cast<const short8*>(wb_half + nc * 512);

      MEGA_K0(b0, b1, 0) MEGA_K0(b1, b0, 1) MEGA_K0(b0, b1, 2) MEGA_K0(b1, b0, 3)
      MEGA_K0(b0, b1, 4) MEGA_K0(b1, b0, 5) MEGA_K0(b0, b1, 6) MEGA_K0(b1, b0, 7)
      __syncthreads();
    }

    // ---- epilogue
    if (!isW2) {
      float rp[4][4];
      #pragma unroll
      for (int mr = 0; mr < 4; ++mr)
        #pragma unroll
        for (int j = 0; j < 4; ++j) rp[mr][j] = 0.f;
      #pragma unroll
      for (int nc = 0; nc < 8; ++nc) {
        const int col = strip * 128 + nc * 16 + l15;
        const float vv = v1[col];
        const float qv = qp1[b * 512 + col];
        #pragma unroll
        for (int mr = 0; mr < 4; ++mr)
          #pragma unroll
          for (int j = 0; j < 4; ++j)
            rp[mr][j] += fast_tanh(acc[mr][nc][j] + qv) * vv;
      }
      #pragma unroll
      for (int off = 1; off < 16; off <<= 1)
        #pragma unroll
        for (int mr = 0; mr < 4; ++mr)
          #pragma unroll
          for (int j = 0; j < 4; ++j)
            rp[mr][j] += __shfl_xor(rp[mr][j], off, 64);
      if (l15 == 0) {
        #pragma unroll
        for (int mr = 0; mr < 4; ++mr)
          #pragma unroll
          for (int j = 0; j < 4; ++j)
            lds_score[wid][mr * 16 + lhi * 4 + j] = rp[mr][j];
      }
    } else {
      // store P2 pre-activation bf16, fragment-native, coalesced 8B/lane
      unsigned short* pt = p2p + (size_t)tile * 32768;
      #pragma unroll
      for (int mr = 0; mr < 4; ++mr)
        #pragma unroll
        for (int nc = 0; nc < 8; ++nc) {
          union { unsigned int u[2]; ushort4 s; } o;
          o.u[0] = cvt_pk_bf16(acc[mr][nc][0], acc[mr][nc][1]);
          o.u[1] = cvt_pk_bf16(acc[mr][nc][2], acc[mr][nc][3]);
          *reinterpret_cast<ushort4*>(
              pt + (size_t)((strip * 32 + mr * 8 + nc) * 64 + lane) * 4) = o.s;
        }
    }
    __syncthreads();
    if (tid < 64)
      scores1[row0 + tid] = lds_score[0][tid] + lds_score[1][tid] +
                            lds_score[2][tid] + lds_score[3][tid];
  }
}

// =====================  FINISHER: out = v2 . tanh(P2 + qp2)  =====================
__global__ __launch_bounds__(256) void finisher_kernel(
    const unsigned short* __restrict__ p2p, const float* __restrict__ v2,
    const float* __restrict__ qp2, float* __restrict__ out) {
  __shared__ float lds_score[4][64];
  const int tid = threadIdx.x, wi = tid >> 6, lane = tid & 63;
  const int l15 = lane & 15, lhi = lane >> 4;
  const int tile = blockIdx.x, row0 = tile * 64, b = row0 >> 11;
  const unsigned short* pt = p2p + (size_t)tile * 32768;
  float rp[4][4];
  #pragma unroll
  for (int mr = 0; mr < 4; ++mr)
    #pragma unroll
    for (int j = 0; j < 4; ++j) rp[mr][j] = 0.f;
  #pragma unroll
  for (int nc = 0; nc < 8; ++nc) {
    const int col = wi * 128 + nc * 16 + l15;
    const float vv = v2[col];
    const float qv = qp2[b * 512 + col];
    #pragma unroll
    for (int mr = 0; mr < 4; ++mr) {
      ushort4 pv = *reinterpret_cast<const ushort4*>(
          pt + (size_t)((wi * 32 + mr * 8 + nc) * 64 + lane) * 4);
      rp[mr][0] += fast_tanh(bf2f(pv.x) + qv) * vv;
      rp[mr][1] += fast_tanh(bf2f(pv.y) + qv) * vv;
      rp[mr][2] += fast_tanh(bf2f(pv.z) + qv) * vv;
      rp[mr][3] += fast_tanh(bf2f(pv.w) + qv) * vv;
    }
  }
  #pragma unroll
  for (int off = 1; off < 16; off <<= 1)
    #pragma unroll
    for (int mr = 0; mr < 4; ++mr)
      #pragma unroll
      for (int j = 0; j < 4; ++j)
        rp[mr][j] += __shfl_xor(rp[mr][j], off, 64);
  if (l15 == 0) {
    #pragma unroll
    for (int mr = 0; mr < 4; ++mr)
      #pragma unroll
      for (int j = 0; j < 4; ++j)
        lds_score[wi][mr * 16 + lhi * 4 + j] = rp[mr][j];
  }
  __syncthreads();
  if (tid < 64)
    out[row0 + tid] = lds_score[0][tid] + lds_score[1][tid] +
                      lds_score[2][tid] + lds_score[3][tid];
}

// =====================  SHARED KERNELS  =====================

__global__ __launch_bounds__(512) void qproj_kernel(
    const float* __restrict__ W, const float* __restrict__ x,
    float* __restrict__ qp) {
  __shared__ float xs[512];
  int b = blockIdx.x, d = threadIdx.x;
  xs[d] = x[b * 512 + d];
  __syncthreads();
  const float4* wr = (const float4*)(W + (size_t)d * 1024 + 512);
  const float4* xv = (const float4*)xs;
  float acc = 0.f;
  #pragma unroll 8
  for (int h = 0; h < 128; ++h) {
    float4 w4 = wr[h], x4 = xv[h];
    acc += w4.x * x4.x + w4.y * x4.y + w4.z * x4.z + w4.w * x4.w;
  }
  qp[b * 512 + d] = acc;
}

__global__ __launch_bounds__(256) void softmax_kernel(float* __restrict__ sc) {
  int b = blockIdx.x, tid = threadIdx.x;
  float* row = sc + (size_t)b * S_DIM;
  float vv[8];
  float m = -1e30f;
  #pragma unroll
  for (int i = 0; i < 8; ++i) { vv[i] = row[tid + i * 256]; m = fmaxf(m, vv[i]); }
  #pragma unroll
  for (int off = 32; off; off >>= 1) m = fmaxf(m, __shfl_xor(m, off, 64));
  __shared__ float red[4], red2[4];
  int wid = tid >> 6, lane = tid & 63;
  if (lane == 0) red[wid] = m;
  __syncthreads();
  m = fmaxf(fmaxf(red[0], red[1]), fmaxf(red[2], red[3]));
  float s = 0.f;
  #pragma unroll
  for (int i = 0; i < 8; ++i) { vv[i] = __expf(vv[i] - m); s += vv[i]; }
  #pragma unroll
  for (int off = 32; off; off >>= 1) s += __shfl_xor(s, off, 64);
  if (lane == 0) red2[wid] = s;
  __syncthreads();
  s = red2[0] + red2[1] + red2[2] + red2[3];
  float inv = 1.f / s;
  #pragma unroll
  for (int i = 0; i < 8; ++i) row[tid + i * 256] = vv[i] * inv;
}

// new_q partials from f32 keys (exact): part[b][sc][:] = sum attn*keys
__global__ __launch_bounds__(512) void wsum_part_kernel(
    const float* __restrict__ keys, const float* __restrict__ attn,
    float* __restrict__ part) {
  int b = blockIdx.x, sc = blockIdx.y;
  int tid = threadIdx.x;
  int c4 = tid & 127, rg = tid >> 7;
  const float* kb = keys + ((size_t)(b * S_DIM + sc * 128 + rg * 32)) * 512 + c4 * 4;
  const float* ab = attn + b * S_DIM + sc * 128 + rg * 32;
  float4 acc = {0.f, 0.f, 0.f, 0.f};
  #pragma unroll 8
  for (int i = 0; i < 32; ++i) {
    float w = ab[i];
    float4 kv = *reinterpret_cast<const float4*>(kb + (size_t)i * 512);
    acc.x += w * kv.x; acc.y += w * kv.y; acc.z += w * kv.z; acc.w += w * kv.w;
  }
  __shared__ float4 red[4][128];
  red[rg][c4] = acc;
  __syncthreads();
  if (tid < 128) {
    float4 a0 = red[0][tid], a1 = red[1][tid], a2 = red[2][tid], a3 = red[3][tid];
    float4 s;
    s.x = a0.x + a1.x + a2.x + a3.x;
    s.y = a0.y + a1.y + a2.y + a3.y;
    s.z = a0.z + a1.z + a2.z + a3.z;
    s.w = a0.w + a1.w + a2.w + a3.w;
    *reinterpret_cast<float4*>(part + ((size_t)b * 16 + sc) * 512 + tid * 4) = s;
  }
}

__global__ __launch_bounds__(512) void wsum_final_kernel(
    const float* __restrict__ part, float* __restrict__ new_q) {
  int b = blockIdx.x, h = threadIdx.x;
  float acc = 0.f;
  #pragma unroll
  for (int sc = 0; sc < 16; ++sc) acc += part[((size_t)b * 16 + sc) * 512 + h];
  new_q[b * 512 + h] = acc;
}

// =====================  FALLBACK PATH (round-2, f32 keys)  =====================

__global__ __launch_bounds__(256) void convw_kernel(
    const float* __restrict__ W1, const float* __restrict__ W2,
    unsigned short* __restrict__ wk1, unsigned short* __restrict__ wk2) {
  int idx = blockIdx.x * 256 + threadIdx.x;
  const float* W = (idx < 262144) ? W1 : W2;
  unsigned short* o = (idx < 262144) ? wk1 : wk2;
  int j = idx & 262143;
  int d = j >> 9, h = j & 511;
  o[j] = f2bf(W[(size_t)d * 1024 + h]);
}

__global__ __launch_bounds__(512, 4) void fused_scores_kernel(
    const float* __restrict__ keys, const unsigned short* __restrict__ wk,
    const float* __restrict__ v, const float* __restrict__ qp,
    float* __restrict__ out) {
  __shared__ __align__(16) unsigned short lds_k[64 * 512];
  __shared__ float lds_score[8][64];
  char* lds_b = (char*)lds_k;
  const int tid  = threadIdx.x;
  const int wid  = tid >> 6;
  const int lane = tid & 63;
  const int l15  = lane & 15;
  const int lhi  = lane >> 4;
  const int row0 = blockIdx.x * 64;
  const int b    = row0 >> 11;
  const int wcol = wid * 64;
  #pragma unroll
  for (int i = 0; i < 8; ++i) {
    int c = i * 512 + tid;
    int r = c >> 6, k = (c & 63) * 8;
    const float* src = keys + (size_t)(row0 + r) * 512 + k;
    const float4 f0 = *reinterpret_cast<const float4*>(src);
    const float4 f1 = *reinterpret_cast<const float4*>(src + 4);
    short8 hv;
    hv[0] = (short)f2bf(f0.x); hv[1] = (short)f2bf(f0.y);
    hv[2] = (short)f2bf(f0.z); hv[3] = (short)f2bf(f0.w);
    hv[4] = (short)f2bf(f1.x); hv[5] = (short)f2bf(f1.y);
    hv[6] = (short)f2bf(f1.z); hv[7] = (short)f2bf(f1.w);
    int byte = (r * 1024 + k * 2) ^ ((r & 7) << 4);
    *reinterpret_cast<short8*>(lds_b + byte) = hv;
  }
  __syncthreads();
  f32x4 acc[4][4];
  #pragma unroll
  for (int mr = 0; mr < 4; ++mr)
    #pragma unroll
    for (int nc = 0; nc < 4; ++nc) {
      f32x4 z = {0.f, 0.f, 0.f, 0.f};
      acc[mr][nc] = z;
    }
  const int koff = lhi * 8;
  #pragma unroll 1
  for (int k0 = 0; k0 < 512; k0 += 32) {
    short8 a[4], bbv[4];
    #pragma unroll
    for (int nc = 0; nc < 4; ++nc) {
      const unsigned short* p =
          wk + (((size_t)(wcol + nc * 16 + l15)) << 9) + k0 + koff;
      bbv[nc] = *reinterpret_cast<const short8*>(p);
    }
    #pragma unroll
    for (int mr = 0; mr < 4; ++mr) {
      int r = mr * 16 + l15;
      int byte = (r * 1024 + (k0 + koff) * 2) ^ ((r & 7) << 4);
      a[mr] = *reinterpret_cast<const short8*>(lds_b + byte);
    }
    #pragma unroll
    for (int mr = 0; mr < 4; ++mr)
      #pragma unroll
      for (int nc = 0; nc < 4; ++nc)
        acc[mr][nc] = __builtin_amdgcn_mfma_f32_16x16x32_bf16(
            a[mr], bbv[nc], acc[mr][nc], 0, 0, 0);
  }
  float rp[4][4];
  #pragma unroll
  for (int mr = 0; mr < 4; ++mr)
    #pragma unroll
    for (int j = 0; j < 4; ++j) rp[mr][j] = 0.f;
  #pragma unroll
  for (int nc = 0; nc < 4; ++nc) {
    int col = wcol + nc * 16 + l15;
    float vv = v[col];
    float qv = qp[b * 512 + col];
    #pragma unroll
    for (int mr = 0; mr < 4; ++mr)
      #pragma unroll
      for (int j = 0; j < 4; ++j)
        rp[mr][j] += fast_tanh(acc[mr][nc][j] + qv) * vv;
  }
  #pragma unroll
  for (int off = 1; off < 16; off <<= 1)
    #pragma unroll
    for (int mr = 0; mr < 4; ++mr)
      #pragma unroll
      for (int j = 0; j < 4; ++j)
        rp[mr][j] += __shfl_xor(rp[mr][j], off, 64);
  if (l15 == 0) {
    #pragma unroll
    for (int mr = 0; mr < 4; ++mr)
      #pragma unroll
      for (int j = 0; j < 4; ++j)
        lds_score[wid][mr * 16 + lhi * 4 + j] = rp[mr][j];
  }
  __syncthreads();
  if (tid < 64) {
    float s = 0.f;
    #pragma unroll
    for (int w = 0; w < 8; ++w) s += lds_score[w][tid];
    out[row0 + tid] = s;
  }
}

// =====================  LAUNCH  =====================

extern "C" void kernel_launch(void* const* d_in, const int* in_sizes, int n_in,
                              void* d_out, int out_size, void* d_ws, size_t ws_size,
                              hipStream_t stream) {
  (void)in_sizes; (void)n_in; (void)out_size;
  const float* keys  = (const float*)d_in[0];
  const float* query = (const float*)d_in[1];
  const float* v1    = (const float*)d_in[2];
  const float* W1    = (const float*)d_in[3];
  const float* v2    = (const float*)d_in[4];
  const float* W2    = (const float*)d_in[5];
  float* out = (float*)d_out;
  float* wsf = (float*)d_ws;

  // fast-path ws (f32 units): qp1|attn|new_q|qp2|part | wkp1,wkp2 (bf16) | p2p (bf16)
  const size_t FAST_NEED = 34570240ull * 4ull;   // ~138.3 MB
  if (ws_size >= FAST_NEED) {
    float* qp1   = wsf;                  // 32768
    float* attn  = wsf + 32768;          // 131072
    float* new_q = wsf + 163840;         // 32768
    float* qp2   = wsf + 196608;         // 32768
    float* part  = wsf + 229376;         // 524288
    unsigned short* wkp1 = (unsigned short*)(wsf + 753664);   // 262144 us
    unsigned short* wkp2 = wkp1 + 262144;                     // -> f-off 1015808
    unsigned short* p2p  = (unsigned short*)(wsf + 1015808);  // 67108864 us

    pack_b_kernel<<<256, 256, 0, stream>>>(W1, W2, wkp1, wkp2);
    qproj_kernel<<<64, 512, 0, stream>>>(W1, query, qp1);
    mega_kernel<<<256, 512, 0, stream>>>(keys, wkp1, wkp2, v1, qp1, attn, p2p);
    softmax_kernel<<<64, 256, 0, stream>>>(attn);
    wsum_part_kernel<<<dim3(64, 16), 512, 0, stream>>>(keys, attn, part);
    wsum_final_kernel<<<64, 512, 0, stream>>>(part, new_q);
    qproj_kernel<<<64, 512, 0, stream>>>(W2, new_q, qp2);
    finisher_kernel<<<2048, 256, 0, stream>>>(p2p, v2, qp2, out);
  } else {
    float* qp1   = wsf;
    float* attn  = wsf + 32768;
    float* new_q = wsf + 163840;
    float* qp2   = wsf + 196608;
    float* part  = wsf + 229376;
    unsigned short* wk1 = (unsigned short*)(wsf + 753664);
    unsigned short* wk2 = wk1 + 262144;

    convw_kernel<<<2048, 256, 0, stream>>>(W1, W2, wk1, wk2);
    qproj_kernel<<<64, 512, 0, stream>>>(W1, query, qp1);
    fused_scores_kernel<<<2048, 512, 0, stream>>>(keys, wk1, v1, qp1, attn);
    softmax_kernel<<<64, 256, 0, stream>>>(attn);
    wsum_part_kernel<<<dim3(64, 16), 512, 0, stream>>>(keys, attn, part);
    wsum_final_kernel<<<64, 512, 0, stream>>>(part, new_q);
    qproj_kernel<<<64, 512, 0, stream>>>(W2, new_q, qp2);
    fused_scores_kernel<<<2048, 512, 0, stream>>>(keys, wk2, v2, qp2, out);
  }
}

// Round 6
// 317.077 us; speedup vs baseline: 2.3727x; 2.3727x over previous
//
#include <hip/hip_runtime.h>
#include <cstdint>
#include <cstddef>

// B=64, S=2048, H=512.  M = B*S = 131072 rows.
#define S_DIM 2048

typedef __attribute__((ext_vector_type(8))) short short8;   // 8 bf16 = 4 VGPR
typedef __attribute__((ext_vector_type(4))) float f32x4;    // MFMA 16x16 accum

static __device__ __forceinline__ unsigned short f2bf(float f) {
  union { float f; unsigned int u; } v; v.f = f;
  unsigned int r = (v.u + 0x7fffu + ((v.u >> 16) & 1u)) >> 16;  // RNE
  return (unsigned short)r;
}

static __device__ __forceinline__ float bf2f(unsigned short u) {
  union { unsigned int u; float f; } v; v.u = ((unsigned int)u) << 16;
  return v.f;
}

static __device__ __forceinline__ float fast_tanh(float x) {
  x = fminf(15.f, fmaxf(-15.f, x));
  float e = __expf(x + x);
  return 1.f - 2.f * __builtin_amdgcn_rcpf(e + 1.f);
}

static __device__ __forceinline__ void gload_lds16(const void* g, void* l) {
  __builtin_amdgcn_global_load_lds(
      (const __attribute__((address_space(1))) void*)g,
      (__attribute__((address_space(3))) void*)l, 16, 0, 0);
}

// =====================  PACKED LAYOUTS (same as round 3/4)  =====================
// Packed A (keys bf16): per 64-row tile t (2048 tiles), chunk wt in [0,4096):
//   k0 = wt>>8, mr = (wt>>6)&3, lhi = (wt>>4)&3, l15 = wt&15
//   akp[t*32768 + wt*8 + e] = keys[t*64 + mr*16 + l15][k0*32 + lhi*8 + e]
// Packed B (wk bf16): wt in [0,32768):
//   k0 = wt>>11, g = (wt>>6)&31, lhi = (wt>>4)&3, l15 = wt&15
//   wkp[wt*8 + e] = W[g*16 + l15][k0*32 + lhi*8 + e]   (keys-half, row stride 1024)

__global__ __launch_bounds__(256) void pack_b_kernel(
    const float* __restrict__ W1, const float* __restrict__ W2,
    unsigned short* __restrict__ wkp1, unsigned short* __restrict__ wkp2) {
  int j = blockIdx.x * 256 + threadIdx.x;            // 0 .. 65535
  const float* W = (j < 32768) ? W1 : W2;
  unsigned short* o = (j < 32768) ? wkp1 : wkp2;
  int wt = j & 32767;
  int k0 = wt >> 11, g = (wt >> 6) & 31, lhi = (wt >> 4) & 3, l15 = wt & 15;
  const float* src = W + (size_t)(g * 16 + l15) * 1024 + k0 * 32 + lhi * 8;
  float4 f0 = *reinterpret_cast<const float4*>(src);
  float4 f1 = *reinterpret_cast<const float4*>(src + 4);
  short8 hv;
  hv[0] = (short)f2bf(f0.x); hv[1] = (short)f2bf(f0.y);
  hv[2] = (short)f2bf(f0.z); hv[3] = (short)f2bf(f0.w);
  hv[4] = (short)f2bf(f1.x); hv[5] = (short)f2bf(f1.y);
  hv[6] = (short)f2bf(f1.z); hv[7] = (short)f2bf(f1.w);
  *reinterpret_cast<short8*>(o + (size_t)wt * 8) = hv;
}

// ---- Stage-1 (Mtile=128): read f32 keys, pack to LDS + akp, MFMA, scores.
// 8 waves; wave owns 128 rows x 64 cols (acc[8][4]). K=512 in 2 halves of 256,
// each half = 64 KB bf16 LDS (2 x 64-row packed tiles). Half-1 staging loads
// are interleaved into half-0's k0 loop (lag-4 writeback).
__global__ __launch_bounds__(512, 2) void fused_pack_scores128_kernel(
    const float* __restrict__ keys, const unsigned short* __restrict__ wkp,
    const float* __restrict__ v, const float* __restrict__ qp,
    unsigned short* __restrict__ akp, float* __restrict__ scores1) {
  __shared__ __align__(16) unsigned short lds_a[2][32768];   // 2 x 64 KB
  __shared__ float lds_score[8][128];

  const int tid  = threadIdx.x;
  const int wid  = tid >> 6;
  const int lane = tid & 63;
  const int l15  = lane & 15;
  const int lhi  = lane >> 4;
  const int blk  = blockIdx.x;          // 0..1023
  const int row0 = blk * 128;
  const int b    = row0 >> 11;
  const int t64  = blk * 2;             // first 64-row akp tile
  const int wcol = wid * 64;

  // staging decode (constant per thread)
  const int sub   = tid & 255;
  const int mr_s  = sub >> 6;
  const int lhi_s = (sub >> 4) & 3;
  const int l15_s = sub & 15;
  const int k0b   = tid >> 8;           // 0 or 1
  const int rowA  = row0 + mr_s * 16 + l15_s;   // T'=0 row; T'=1 adds 64

  const unsigned short* wbase = wkp + (size_t)wid * 2048 + (size_t)lane * 8;

#define S1_WRITE_CHUNK(I, HK)                                                  \
  {                                                                            \
    const int Tp_  = (I) >> 2;                                                 \
    const int k0l_ = ((I) * 2 + k0b) & 7;                                      \
    const int c_   = (I) * 512 + tid;                                          \
    short8 hv;                                                                 \
    hv[0] = (short)f2bf(f[I][0].x); hv[1] = (short)f2bf(f[I][0].y);            \
    hv[2] = (short)f2bf(f[I][0].z); hv[3] = (short)f2bf(f[I][0].w);            \
    hv[4] = (short)f2bf(f[I][1].x); hv[5] = (short)f2bf(f[I][1].y);            \
    hv[6] = (short)f2bf(f[I][1].z); hv[7] = (short)f2bf(f[I][1].w);            \
    *reinterpret_cast<short8*>(&lds_a[HK][c_ * 8]) = hv;                       \
    *reinterpret_cast<short8*>(                                                \
        akp + (size_t)(t64 + Tp_) * 32768 +                                    \
        ((size_t)((HK) * 8 + k0l_) * 256 + sub) * 8) = hv;                     \
  }

  // ---- prologue: stage half0 -> buf0 (all loads first, then writes)
  {
    float4 f[8][2];
    #pragma unroll
    for (int i = 0; i < 8; ++i) {
      const int Tp  = i >> 2;
      const int k0l = (i * 2 + k0b) & 7;
      const float* src =
          keys + (size_t)(rowA + Tp * 64) * 512 + k0l * 32 + lhi_s * 8;
      f[i][0] = *reinterpret_cast<const float4*>(src);
      f[i][1] = *reinterpret_cast<const float4*>(src + 4);
    }
    #pragma unroll
    for (int i = 0; i < 8; ++i) S1_WRITE_CHUNK(i, 0)
  }
  __syncthreads();

  f32x4 acc[8][4];
  #pragma unroll
  for (int mr2 = 0; mr2 < 8; ++mr2)
    #pragma unroll
    for (int nc = 0; nc < 4; ++nc) {
      f32x4 z = {0.f, 0.f, 0.f, 0.f};
      acc[mr2][nc] = z;
    }

  // ---- compute half0, interleaving half1 stage loads (lag-4 writeback)
  {
    float4 f[8][2];
    #pragma unroll
    for (int j = 0; j < 8; ++j) {
      short8 bbv[4];
      #pragma unroll
      for (int nc = 0; nc < 4; ++nc)
        bbv[nc] = *reinterpret_cast<const short8*>(
            wbase + (size_t)j * 16384 + nc * 512);
      // issue half1 stage loads for chunk j
      {
        const int Tp  = j >> 2;
        const int k0l = (j * 2 + k0b) & 7;
        const float* src =
            keys + (size_t)(rowA + Tp * 64) * 512 + 256 + k0l * 32 + lhi_s * 8;
        f[j][0] = *reinterpret_cast<const float4*>(src);
        f[j][1] = *reinterpret_cast<const float4*>(src + 4);
      }
      #pragma unroll
      for (int mr2 = 0; mr2 < 8; ++mr2) {
        const short8 a = *reinterpret_cast<const short8*>(
            &lds_a[0][((mr2 >> 2) * 2048 + j * 256 + (mr2 & 3) * 64 + lane) * 8]);
        #pragma unroll
        for (int nc = 0; nc < 4; ++nc)
          acc[mr2][nc] = __builtin_amdgcn_mfma_f32_16x16x32_bf16(
              a, bbv[nc], acc[mr2][nc], 0, 0, 0);
      }
      if (j >= 4) { const int i = j - 4; S1_WRITE_CHUNK(i, 1) }
    }
    #pragma unroll
    for (int i = 4; i < 8; ++i) S1_WRITE_CHUNK(i, 1)
  }
  __syncthreads();

  // ---- compute half1
  #pragma unroll
  for (int j = 0; j < 8; ++j) {
    short8 bbv[4];
    #pragma unroll
    for (int nc = 0; nc < 4; ++nc)
      bbv[nc] = *reinterpret_cast<const short8*>(
          wbase + (size_t)(8 + j) * 16384 + nc * 512);
    #pragma unroll
    for (int mr2 = 0; mr2 < 8; ++mr2) {
      const short8 a = *reinterpret_cast<const short8*>(
          &lds_a[1][((mr2 >> 2) * 2048 + j * 256 + (mr2 & 3) * 64 + lane) * 8]);
      #pragma unroll
      for (int nc = 0; nc < 4; ++nc)
        acc[mr2][nc] = __builtin_amdgcn_mfma_f32_16x16x32_bf16(
            a, bbv[nc], acc[mr2][nc], 0, 0, 0);
    }
  }

  // ---- epilogue: tanh(acc+qp)*v, per-row reduce, write scores
  float rp[8][4];
  #pragma unroll
  for (int mr2 = 0; mr2 < 8; ++mr2)
    #pragma unroll
    for (int j = 0; j < 4; ++j) rp[mr2][j] = 0.f;
  #pragma unroll
  for (int nc = 0; nc < 4; ++nc) {
    const int col = wcol + nc * 16 + l15;
    const float vv = v[col];
    const float qv = qp[b * 512 + col];
    #pragma unroll
    for (int mr2 = 0; mr2 < 8; ++mr2)
      #pragma unroll
      for (int j = 0; j < 4; ++j)
        rp[mr2][j] += fast_tanh(acc[mr2][nc][j] + qv) * vv;
  }
  #pragma unroll
  for (int off = 1; off < 16; off <<= 1)
    #pragma unroll
    for (int mr2 = 0; mr2 < 8; ++mr2)
      #pragma unroll
      for (int j = 0; j < 4; ++j)
        rp[mr2][j] += __shfl_xor(rp[mr2][j], off, 64);
  if (l15 == 0) {
    #pragma unroll
    for (int mr2 = 0; mr2 < 8; ++mr2)
      #pragma unroll
      for (int j = 0; j < 4; ++j)
        lds_score[wid][mr2 * 16 + lhi * 4 + j] = rp[mr2][j];
  }
  __syncthreads();
  if (tid < 128) {
    float s = 0.f;
    #pragma unroll
    for (int w = 0; w < 8; ++w) s += lds_score[w][tid];
    scores1[row0 + tid] = s;
  }
#undef S1_WRITE_CHUNK
}

// ---- Stage-2 (Mtile=128): packed A via global_load_lds DMA, interleaved.
__global__ __launch_bounds__(512, 2) void fused_packed128_kernel(
    const unsigned short* __restrict__ akp, const unsigned short* __restrict__ wkp,
    const float* __restrict__ v, const float* __restrict__ qp,
    float* __restrict__ out) {
  __shared__ __align__(16) unsigned short lds_a[2][32768];   // 2 x 64 KB
  __shared__ float lds_score[8][128];

  const int tid  = threadIdx.x;
  const int wid  = tid >> 6;
  const int lane = tid & 63;
  const int l15  = lane & 15;
  const int lhi  = lane >> 4;
  const int blk  = blockIdx.x;
  const int row0 = blk * 128;
  const int b    = row0 >> 11;
  const int t64  = blk * 2;
  const int wcol = wid * 64;

  const int sub = tid & 255;
  const int k0b = tid >> 8;
  const unsigned short* at = akp + (size_t)t64 * 32768;
  const unsigned short* wbase = wkp + (size_t)wid * 2048 + (size_t)lane * 8;

  // prologue: DMA half0 -> buf0
  #pragma unroll
  for (int i = 0; i < 8; ++i) {
    const int Tp  = i >> 2;
    const int k0l = (i * 2 + k0b) & 7;
    const int c   = i * 512 + tid;
    gload_lds16(at + (size_t)Tp * 32768 + ((size_t)k0l * 256 + sub) * 8,
                (char*)&lds_a[0][0] + c * 16);
  }
  __syncthreads();

  f32x4 acc[8][4];
  #pragma unroll
  for (int mr2 = 0; mr2 < 8; ++mr2)
    #pragma unroll
    for (int nc = 0; nc < 4; ++nc) {
      f32x4 z = {0.f, 0.f, 0.f, 0.f};
      acc[mr2][nc] = z;
    }

  // compute half0, interleaving half1 DMA (1 chunk per k0 step, after B loads)
  #pragma unroll
  for (int j = 0; j < 8; ++j) {
    short8 bbv[4];
    #pragma unroll
    for (int nc = 0; nc < 4; ++nc)
      bbv[nc] = *reinterpret_cast<const short8*>(
          wbase + (size_t)j * 16384 + nc * 512);
    {
      const int Tp  = j >> 2;
      const int k0l = (j * 2 + k0b) & 7;
      const int c   = j * 512 + tid;
      gload_lds16(at + (size_t)Tp * 32768 + ((size_t)(8 + k0l) * 256 + sub) * 8,
                  (char*)&lds_a[1][0] + c * 16);
    }
    #pragma unroll
    for (int mr2 = 0; mr2 < 8; ++mr2) {
      const short8 a = *reinterpret_cast<const short8*>(
          &lds_a[0][((mr2 >> 2) * 2048 + j * 256 + (mr2 & 3) * 64 + lane) * 8]);
      #pragma unroll
      for (int nc = 0; nc < 4; ++nc)
        acc[mr2][nc] = __builtin_amdgcn_mfma_f32_16x16x32_bf16(
            a, bbv[nc], acc[mr2][nc], 0, 0, 0);
    }
  }
  __syncthreads();   // drains half1 DMA

  #pragma unroll
  for (int j = 0; j < 8; ++j) {
    short8 bbv[4];
    #pragma unroll
    for (int nc = 0; nc < 4; ++nc)
      bbv[nc] = *reinterpret_cast<const short8*>(
          wbase + (size_t)(8 + j) * 16384 + nc * 512);
    #pragma unroll
    for (int mr2 = 0; mr2 < 8; ++mr2) {
      const short8 a = *reinterpret_cast<const short8*>(
          &lds_a[1][((mr2 >> 2) * 2048 + j * 256 + (mr2 & 3) * 64 + lane) * 8]);
      #pragma unroll
      for (int nc = 0; nc < 4; ++nc)
        acc[mr2][nc] = __builtin_amdgcn_mfma_f32_16x16x32_bf16(
            a, bbv[nc], acc[mr2][nc], 0, 0, 0);
    }
  }

  float rp[8][4];
  #pragma unroll
  for (int mr2 = 0; mr2 < 8; ++mr2)
    #pragma unroll
    for (int j = 0; j < 4; ++j) rp[mr2][j] = 0.f;
  #pragma unroll
  for (int nc = 0; nc < 4; ++nc) {
    const int col = wcol + nc * 16 + l15;
    const float vv = v[col];
    const float qv = qp[b * 512 + col];
    #pragma unroll
    for (int mr2 = 0; mr2 < 8; ++mr2)
      #pragma unroll
      for (int j = 0; j < 4; ++j)
        rp[mr2][j] += fast_tanh(acc[mr2][nc][j] + qv) * vv;
  }
  #pragma unroll
  for (int off = 1; off < 16; off <<= 1)
    #pragma unroll
    for (int mr2 = 0; mr2 < 8; ++mr2)
      #pragma unroll
      for (int j = 0; j < 4; ++j)
        rp[mr2][j] += __shfl_xor(rp[mr2][j], off, 64);
  if (l15 == 0) {
    #pragma unroll
    for (int mr2 = 0; mr2 < 8; ++mr2)
      #pragma unroll
      for (int j = 0; j < 4; ++j)
        lds_score[wid][mr2 * 16 + lhi * 4 + j] = rp[mr2][j];
  }
  __syncthreads();
  if (tid < 128) {
    float s = 0.f;
    #pragma unroll
    for (int w = 0; w < 8; ++w) s += lds_score[w][tid];
    out[row0 + tid] = s;
  }
}

// new_q[b][h] = sum_s attn[b,s] * keys[b,s,h], reading packed bf16 keys (round 3).
__global__ __launch_bounds__(256) void wsum_packed_kernel(
    const unsigned short* __restrict__ akp, const float* __restrict__ attn,
    float* __restrict__ new_q) {
  int b = blockIdx.x, k0 = blockIdx.y;
  int t = threadIdx.x;
  int mr = t >> 6, lhi = (t >> 4) & 3, l15 = t & 15;
  const unsigned short* base =
      akp + (size_t)b * 32 * 32768 + (size_t)k0 * 2048 + (size_t)t * 8;
  const float* ab = attn + b * S_DIM + mr * 16 + l15;
  float acc[8];
  #pragma unroll
  for (int e = 0; e < 8; ++e) acc[e] = 0.f;
  #pragma unroll 4
  for (int tile = 0; tile < 32; ++tile) {
    short8 kv = *reinterpret_cast<const short8*>(base + (size_t)tile * 32768);
    float w = ab[tile * 64];
    #pragma unroll
    for (int e = 0; e < 8; ++e)
      acc[e] += w * bf2f((unsigned short)kv[e]);
  }
  __shared__ float red[4][64][8];   // [lhi][row-slot][e]
  #pragma unroll
  for (int e = 0; e < 8; ++e) red[lhi][mr * 16 + l15][e] = acc[e];
  __syncthreads();
  if (t < 32) {
    int lh = t >> 3, e = t & 7;
    float s = 0.f;
    #pragma unroll 8
    for (int r = 0; r < 64; ++r) s += red[lh][r][e];
    new_q[b * 512 + k0 * 32 + lh * 8 + e] = s;
  }
}

// =====================  SHARED KERNELS  =====================

__global__ __launch_bounds__(512) void qproj_kernel(
    const float* __restrict__ W, const float* __restrict__ x,
    float* __restrict__ qp) {
  __shared__ float xs[512];
  int b = blockIdx.x, d = threadIdx.x;
  xs[d] = x[b * 512 + d];
  __syncthreads();
  const float4* wr = (const float4*)(W + (size_t)d * 1024 + 512);
  const float4* xv = (const float4*)xs;
  float acc = 0.f;
  #pragma unroll 8
  for (int h = 0; h < 128; ++h) {
    float4 w4 = wr[h], x4 = xv[h];
    acc += w4.x * x4.x + w4.y * x4.y + w4.z * x4.z + w4.w * x4.w;
  }
  qp[b * 512 + d] = acc;
}

__global__ __launch_bounds__(256) void softmax_kernel(float* __restrict__ sc) {
  int b = blockIdx.x, tid = threadIdx.x;
  float* row = sc + (size_t)b * S_DIM;
  float vv[8];
  float m = -1e30f;
  #pragma unroll
  for (int i = 0; i < 8; ++i) { vv[i] = row[tid + i * 256]; m = fmaxf(m, vv[i]); }
  #pragma unroll
  for (int off = 32; off; off >>= 1) m = fmaxf(m, __shfl_xor(m, off, 64));
  __shared__ float red[4], red2[4];
  int wid = tid >> 6, lane = tid & 63;
  if (lane == 0) red[wid] = m;
  __syncthreads();
  m = fmaxf(fmaxf(red[0], red[1]), fmaxf(red[2], red[3]));
  float s = 0.f;
  #pragma unroll
  for (int i = 0; i < 8; ++i) { vv[i] = __expf(vv[i] - m); s += vv[i]; }
  #pragma unroll
  for (int off = 32; off; off >>= 1) s += __shfl_xor(s, off, 64);
  if (lane == 0) red2[wid] = s;
  __syncthreads();
  s = red2[0] + red2[1] + red2[2] + red2[3];
  float inv = 1.f / s;
  #pragma unroll
  for (int i = 0; i < 8; ++i) row[tid + i * 256] = vv[i] * inv;
}

// =====================  FALLBACK PATH (round-2, f32 keys)  =====================

__global__ __launch_bounds__(256) void convw_kernel(
    const float* __restrict__ W1, const float* __restrict__ W2,
    unsigned short* __restrict__ wk1, unsigned short* __restrict__ wk2) {
  int idx = blockIdx.x * 256 + threadIdx.x;
  const float* W = (idx < 262144) ? W1 : W2;
  unsigned short* o = (idx < 262144) ? wk1 : wk2;
  int j = idx & 262143;
  int d = j >> 9, h = j & 511;
  o[j] = f2bf(W[(size_t)d * 1024 + h]);
}

__global__ __launch_bounds__(512, 4) void fused_scores_kernel(
    const float* __restrict__ keys, const unsigned short* __restrict__ wk,
    const float* __restrict__ v, const float* __restrict__ qp,
    float* __restrict__ out) {
  __shared__ __align__(16) unsigned short lds_k[64 * 512];
  __shared__ float lds_score[8][64];
  char* lds_b = (char*)lds_k;
  const int tid  = threadIdx.x;
  const int wid  = tid >> 6;
  const int lane = tid & 63;
  const int l15  = lane & 15;
  const int lhi  = lane >> 4;
  const int row0 = blockIdx.x * 64;
  const int b    = row0 >> 11;
  const int wcol = wid * 64;
  #pragma unroll
  for (int i = 0; i < 8; ++i) {
    int c = i * 512 + tid;
    int r = c >> 6, k = (c & 63) * 8;
    const float* src = keys + (size_t)(row0 + r) * 512 + k;
    const float4 f0 = *reinterpret_cast<const float4*>(src);
    const float4 f1 = *reinterpret_cast<const float4*>(src + 4);
    short8 hv;
    hv[0] = (short)f2bf(f0.x); hv[1] = (short)f2bf(f0.y);
    hv[2] = (short)f2bf(f0.z); hv[3] = (short)f2bf(f0.w);
    hv[4] = (short)f2bf(f1.x); hv[5] = (short)f2bf(f1.y);
    hv[6] = (short)f2bf(f1.z); hv[7] = (short)f2bf(f1.w);
    int byte = (r * 1024 + k * 2) ^ ((r & 7) << 4);
    *reinterpret_cast<short8*>(lds_b + byte) = hv;
  }
  __syncthreads();
  f32x4 acc[4][4];
  #pragma unroll
  for (int mr = 0; mr < 4; ++mr)
    #pragma unroll
    for (int nc = 0; nc < 4; ++nc) {
      f32x4 z = {0.f, 0.f, 0.f, 0.f};
      acc[mr][nc] = z;
    }
  const int koff = lhi * 8;
  #pragma unroll 1
  for (int k0 = 0; k0 < 512; k0 += 32) {
    short8 a[4], bbv[4];
    #pragma unroll
    for (int nc = 0; nc < 4; ++nc) {
      const unsigned short* p =
          wk + (((size_t)(wcol + nc * 16 + l15)) << 9) + k0 + koff;
      bbv[nc] = *reinterpret_cast<const short8*>(p);
    }
    #pragma unroll
    for (int mr = 0; mr < 4; ++mr) {
      int r = mr * 16 + l15;
      int byte = (r * 1024 + (k0 + koff) * 2) ^ ((r & 7) << 4);
      a[mr] = *reinterpret_cast<const short8*>(lds_b + byte);
    }
    #pragma unroll
    for (int mr = 0; mr < 4; ++mr)
      #pragma unroll
      for (int nc = 0; nc < 4; ++nc)
        acc[mr][nc] = __builtin_amdgcn_mfma_f32_16x16x32_bf16(
            a[mr], bbv[nc], acc[mr][nc], 0, 0, 0);
  }
  float rp[4][4];
  #pragma unroll
  for (int mr = 0; mr < 4; ++mr)
    #pragma unroll
    for (int j = 0; j < 4; ++j) rp[mr][j] = 0.f;
  #pragma unroll
  for (int nc = 0; nc < 4; ++nc) {
    int col = wcol + nc * 16 + l15;
    float vv = v[col];
    float qv = qp[b * 512 + col];
    #pragma unroll
    for (int mr = 0; mr < 4; ++mr)
      #pragma unroll
      for (int j = 0; j < 4; ++j)
        rp[mr][j] += fast_tanh(acc[mr][nc][j] + qv) * vv;
  }
  #pragma unroll
  for (int off = 1; off < 16; off <<= 1)
    #pragma unroll
    for (int mr = 0; mr < 4; ++mr)
      #pragma unroll
      for (int j = 0; j < 4; ++j)
        rp[mr][j] += __shfl_xor(rp[mr][j], off, 64);
  if (l15 == 0) {
    #pragma unroll
    for (int mr = 0; mr < 4; ++mr)
      #pragma unroll
      for (int j = 0; j < 4; ++j)
        lds_score[wid][mr * 16 + lhi * 4 + j] = rp[mr][j];
  }
  __syncthreads();
  if (tid < 64) {
    float s = 0.f;
    #pragma unroll
    for (int w = 0; w < 8; ++w) s += lds_score[w][tid];
    out[row0 + tid] = s;
  }
}

__global__ __launch_bounds__(512) void wsum_part_kernel(
    const float* __restrict__ keys, const float* __restrict__ attn,
    float* __restrict__ part) {
  int b = blockIdx.x, sc = blockIdx.y;
  int tid = threadIdx.x;
  int c4 = tid & 127, rg = tid >> 7;
  const float* kb = keys + ((size_t)(b * S_DIM + sc * 128 + rg * 32)) * 512 + c4 * 4;
  const float* ab = attn + b * S_DIM + sc * 128 + rg * 32;
  float4 acc = {0.f, 0.f, 0.f, 0.f};
  #pragma unroll 8
  for (int i = 0; i < 32; ++i) {
    float w = ab[i];
    float4 kv = *reinterpret_cast<const float4*>(kb + (size_t)i * 512);
    acc.x += w * kv.x; acc.y += w * kv.y; acc.z += w * kv.z; acc.w += w * kv.w;
  }
  __shared__ float4 red[4][128];
  red[rg][c4] = acc;
  __syncthreads();
  if (tid < 128) {
    float4 a0 = red[0][tid], a1 = red[1][tid], a2 = red[2][tid], a3 = red[3][tid];
    float4 s;
    s.x = a0.x + a1.x + a2.x + a3.x;
    s.y = a0.y + a1.y + a2.y + a3.y;
    s.z = a0.z + a1.z + a2.z + a3.z;
    s.w = a0.w + a1.w + a2.w + a3.w;
    *reinterpret_cast<float4*>(part + ((size_t)b * 16 + sc) * 512 + tid * 4) = s;
  }
}

__global__ __launch_bounds__(512) void wsum_final_kernel(
    const float* __restrict__ part, float* __restrict__ new_q) {
  int b = blockIdx.x, h = threadIdx.x;
  float acc = 0.f;
  #pragma unroll
  for (int sc = 0; sc < 16; ++sc) acc += part[((size_t)b * 16 + sc) * 512 + h];
  new_q[b * 512 + h] = acc;
}

// =====================  LAUNCH  =====================

extern "C" void kernel_launch(void* const* d_in, const int* in_sizes, int n_in,
                              void* d_out, int out_size, void* d_ws, size_t ws_size,
                              hipStream_t stream) {
  (void)in_sizes; (void)n_in; (void)out_size;
  const float* keys  = (const float*)d_in[0];
  const float* query = (const float*)d_in[1];
  const float* v1    = (const float*)d_in[2];
  const float* W1    = (const float*)d_in[3];
  const float* v2    = (const float*)d_in[4];
  const float* W2    = (const float*)d_in[5];
  float* out = (float*)d_out;
  float* wsf = (float*)d_ws;

  // fast-path workspace: qp1|attn|new_q|qp2 (f32) | wkp1,wkp2 (bf16) | akp (bf16)
  const size_t FAST_NEED = 491520ull * 4ull + 67108864ull * 2ull;  // ~136.2 MB
  if (ws_size >= FAST_NEED) {
    float* qp1   = wsf;                  // 32768
    float* attn  = wsf + 32768;          // 131072
    float* new_q = wsf + 163840;         // 32768
    float* qp2   = wsf + 196608;         // 32768
    unsigned short* wkp1 = (unsigned short*)(wsf + 229376);  // 262144 us
    unsigned short* wkp2 = wkp1 + 262144;                    // ends at f-off 491520
    unsigned short* akp  = (unsigned short*)(wsf + 491520);  // 67108864 us

    pack_b_kernel<<<256, 256, 0, stream>>>(W1, W2, wkp1, wkp2);
    qproj_kernel<<<64, 512, 0, stream>>>(W1, query, qp1);
    fused_pack_scores128_kernel<<<1024, 512, 0, stream>>>(
        keys, wkp1, v1, qp1, akp, attn);
    softmax_kernel<<<64, 256, 0, stream>>>(attn);
    wsum_packed_kernel<<<dim3(64, 16), 256, 0, stream>>>(akp, attn, new_q);
    qproj_kernel<<<64, 512, 0, stream>>>(W2, new_q, qp2);
    fused_packed128_kernel<<<1024, 512, 0, stream>>>(akp, wkp2, v2, qp2, out);
  } else {
    float* qp1   = wsf;
    float* attn  = wsf + 32768;
    float* new_q = wsf + 163840;
    float* qp2   = wsf + 196608;
    float* part  = wsf + 229376;
    unsigned short* wk1 = (unsigned short*)(wsf + 753664);
    unsigned short* wk2 = wk1 + 262144;

    convw_kernel<<<2048, 256, 0, stream>>>(W1, W2, wk1, wk2);
    qproj_kernel<<<64, 512, 0, stream>>>(W1, query, qp1);
    fused_scores_kernel<<<2048, 512, 0, stream>>>(keys, wk1, v1, qp1, attn);
    softmax_kernel<<<64, 256, 0, stream>>>(attn);
    wsum_part_kernel<<<dim3(64, 16), 512, 0, stream>>>(keys, attn, part);
    wsum_final_kernel<<<64, 512, 0, stream>>>(part, new_q);
    qproj_kernel<<<64, 512, 0, stream>>>(W2, new_q, qp2);
    fused_scores_kernel<<<2048, 512, 0, stream>>>(keys, wk2, v2, qp2, out);
  }
}